// Round 8
// baseline (3952.617 us; speedup 1.0000x reference)
//
#include <hip/hip_runtime.h>
#include <hip/hip_fp16.h>

// LSTM: B=256, S=4096, D=64, H=128 (4H=512 gate cols, layout [i|f|g|o]).
// One batch element per block (256 blocks = 1/CU).
// 512 threads = 8 waves (2 waves/SIMD): wave w owns units 16w..16w+15.
// lane = 16*gate + m (gate 0..3 = i,f,g,o); u = 16*wave + m.
// Each thread owns ONE gate column: 96 packed-half2 weight regs (K=192) ->
// demand ~140 fits arch VGPRs (kills the v_accvgpr_read-per-use tax that
// pins the 256-thread variants at ~3170 us; R7's asm error proved AGPR home).
// Dot engine: __builtin_amdgcn_fdot2 when available (compiler owns hazard
// insertion); fallback inline asm. Both use TWO interleaved accumulator
// chains {RL; dotA; RL; dotB} (dependent-dot spacing 4) — the pattern shared
// by every numerically-passing round (1/3/6), unlike R4/R5's 1-apart chain.
// Gate combine via LDS gather (Ag[512]) + barrier; h via double-buffered LDS.

#define LSTM_B 256
#define LSTM_S 4096
#define LSTM_D 64
#define LSTM_H 128
#define LSTM_G 512

typedef unsigned int u32;
typedef _Float16 half2_t __attribute__((ext_vector_type(2)));

__device__ __forceinline__ u32 pack2h(float lo, float hi) {
  __half2 h = __floats2half2_rn(lo, hi);   // lo -> bits [15:0]
  return *reinterpret_cast<u32*>(&h);
}

#if __has_builtin(__builtin_amdgcn_fdot2)
// acc += dot(half2(a), half2(w)); compiler handles operand classes + hazards.
__device__ __forceinline__ float dot2_f16(float acc, int a_u, u32 w) {
  return __builtin_amdgcn_fdot2(__builtin_bit_cast(half2_t, a_u),
                                __builtin_bit_cast(half2_t, w), acc, false);
}
#else
__device__ __forceinline__ float dot2_f16(float acc, int a_u, u32 w) {
  asm("v_dot2_f32_f16 %0, %1, %2, %0" : "+v"(acc) : "s"(a_u), "v"(w));
  return acc;
}
#endif

__global__ __launch_bounds__(512, 2)
void lstm_fused_kernel(const float* __restrict__ x,
                       const float* __restrict__ Wi,
                       const float* __restrict__ Wh,
                       const float* __restrict__ bh,
                       const float* __restrict__ Wo,
                       const float* __restrict__ bo,
                       float* __restrict__ out) {
  const int t    = threadIdx.x;        // 0..511
  const int lane = t & 63;
  const int wv   = t >> 6;             // wave 0..7
  const int m    = lane & 15;          // unit offset within wave
  const int g    = lane >> 4;          // gate 0..3 = (i, f, g, o)
  const int u    = 16 * wv + m;        // unit id 0..127
  const int b    = blockIdx.x;

  __shared__ float  Ag[LSTM_G];        // gate activations, [i|f|g|o]
  __shared__ __half Hh[2][LSTM_H];     // double-buffered published h (fp16)
  __shared__ float  R[LSTM_H];         // final reduce

  const int col = 128 * g + u;         // gate column in [i|f|g|o] layout

  // ---- stage one gate column into VGPRs as packed half2 over K=192 ----
  u32 wC[96];
  #pragma unroll
  for (int ch = 0; ch < 8; ++ch) {     // Wh: 64 row-pairs
    #pragma unroll
    for (int uu = 0; uu < 8; ++uu) {
      const int j = ch * 8 + uu;
      wC[j] = pack2h(Wh[(2 * j) * LSTM_G + col], Wh[(2 * j + 1) * LSTM_G + col]);
    }
    __builtin_amdgcn_sched_barrier(0);
  }
  #pragma unroll
  for (int ch = 0; ch < 4; ++ch) {     // Wi: 32 row-pairs
    #pragma unroll
    for (int uu = 0; uu < 8; ++uu) {
      const int k = ch * 8 + uu;
      wC[64 + k] = pack2h(Wi[(2 * k) * LSTM_G + col], Wi[(2 * k + 1) * LSTM_G + col]);
    }
    __builtin_amdgcn_sched_barrier(0);
  }

  const float bz = bh[col];
  // activation blend:
  //   gate==2 (cell, tanh):  r=rcp(1+exp2( 2.885*z)); a = 1 + (-2)*r
  //   else (sigmoid):        r=rcp(1+exp2(-1.443*z)); a = 0 + ( 1)*r
  const float kG = (g == 2) ? 2.88539008f : -1.44269504f;
  const float AG = (g == 2) ? 1.0f : 0.0f;
  const float BG = (g == 2) ? -2.0f : 1.0f;

  const float* xb = x + (size_t)b * (LSTM_S * LSTM_D);
  const int xl = lane & 31;            // lanes 32..63 mirror 0..31 (harmless)

  float2 xv0 = *reinterpret_cast<const float2*>(xb + 2 * xl);   // x(0)
  u32 xpair = pack2h(xv0.x, xv0.y);
  u32 hpair = 0u;                      // h0 = 0
  float c = 0.0f, hval = 0.0f;
  __builtin_amdgcn_sched_barrier(0);
  __syncthreads();

  for (int s = 0; s < LSTM_S; ++s) {
    // prefetch next step's x pair (latency hidden under the dot chain)
    const int sn = (s + 1 < LSTM_S) ? s + 1 : s;
    float2 xnv = *reinterpret_cast<const float2*>(xb + (size_t)sn * LSTM_D + 2 * xl);

    // z = bz + W.col dot [h;x], two interleaved chains (A: even j, B: odd j)
    float accA = bz, accB = 0.0f;
    #pragma unroll
    for (int j = 0; j < 32; ++j) {     // h rows: pairs 0..63
      int h0 = __builtin_amdgcn_readlane((int)hpair, 2 * j);
      accA = dot2_f16(accA, h0, wC[2 * j]);
      int h1 = __builtin_amdgcn_readlane((int)hpair, 2 * j + 1);
      accB = dot2_f16(accB, h1, wC[2 * j + 1]);
    }
    #pragma unroll
    for (int j = 0; j < 16; ++j) {     // x rows: pairs 0..31
      int x0 = __builtin_amdgcn_readlane((int)xpair, 2 * j);
      accA = dot2_f16(accA, x0, wC[64 + 2 * j]);
      int x1 = __builtin_amdgcn_readlane((int)xpair, 2 * j + 1);
      accB = dot2_f16(accB, x1, wC[64 + 2 * j + 1]);
    }
    const float acc = accA + accB;

    const float r1 = __builtin_amdgcn_rcpf(1.0f + __builtin_amdgcn_exp2f(kG * acc));
    const float a  = AG + BG * r1;       // activation of this thread's gate

    Ag[col] = a;                         // publish gate activation
    __syncthreads();                     // barrier 1

    if (g == 0) {                        // unit owner: a == i_u
      const float fv = Ag[LSTM_H + u];
      const float gv = Ag[2 * LSTM_H + u];
      const float ov = Ag[3 * LSTM_H + u];
      c = fv * c + a * gv;               // c = f*c + i*g
      hval = ov * (1.0f - 2.0f * __builtin_amdgcn_rcpf(
                       1.0f + __builtin_amdgcn_exp2f(2.88539008f * c)));
      Hh[(s + 1) & 1][u] = __float2half(hval);
    }
    __syncthreads();                     // barrier 2

    hpair = *reinterpret_cast<const u32*>(
        reinterpret_cast<const char*>(Hh[(s + 1) & 1]) + 4 * lane);
    xpair = pack2h(xnv.x, xnv.y);
  }

  // ---- output: out[b] = h_last @ Wo + bo ----
  if (g == 0) R[u] = hval * Wo[u];
  __syncthreads();
  if (t < 64) {
    float v = R[t] + R[t + 64];
    #pragma unroll
    for (int off = 32; off; off >>= 1) v += __shfl_down(v, off);
    if (t == 0) out[b] = v + bo[0];
  }
}

extern "C" void kernel_launch(void* const* d_in, const int* in_sizes, int n_in,
                              void* d_out, int out_size, void* d_ws, size_t ws_size,
                              hipStream_t stream) {
  const float* x  = (const float*)d_in[0];
  const float* Wi = (const float*)d_in[1];
  const float* Wh = (const float*)d_in[2];
  const float* bh = (const float*)d_in[3];
  const float* Wo = (const float*)d_in[4];
  const float* bo = (const float*)d_in[5];
  float* out = (float*)d_out;

  lstm_fused_kernel<<<LSTM_B, 512, 0, stream>>>(x, Wi, Wh, bh, Wo, bo, out);
}

// Round 9
// 2664.863 us; speedup vs baseline: 1.4832x; 1.4832x over previous
//
#include <hip/hip_runtime.h>
#include <hip/hip_fp16.h>

// LSTM: B=256, S=4096, D=64, H=128 (4H=512 gate cols [i|f|g|o]), K=192=[h;x].
// One batch element per block (256 blocks = 1/CU), 512 threads = 8 waves.
// z = [h;x] @ [Wh;Wi] via v_mfma_f32_16x16x32_f16: A = hx broadcast into row 0
// (rows 1-15 read a zeroed LDS region), B = per-wave resident weight
// fragments (wave w owns cols [64w,64w+64): 4 n-tiles x 6 k-steps x 4 VGPRs).
// AGPR-homing of the weight array is now FINE: MFMA reads AGPRs natively
// (R7 proved VALU dots cannot -> R1..R8's ~1500 cyc/step copy/mov tax).
// k-slot mapping cancellation: A and B are staged with the SAME
// (lane-group, elem) -> k map, so only row/col = lane%16 (universal) and the
// C/D layout (HW-verified: col=lane&15, row=(lane>>4)*4+reg) must be correct.
// h kept fp16 (proven absmax 4.88e-4); activation/c/h formulas identical to
// the passing rounds.

#define LSTM_B 256
#define LSTM_S 4096
#define LSTM_D 64
#define LSTM_H 128
#define LSTM_G 512
#define LSTM_K 192

typedef unsigned int u32;
typedef _Float16 f16x8 __attribute__((ext_vector_type(8)));
typedef float f32x4 __attribute__((ext_vector_type(4)));

__device__ __forceinline__ float sigm(float z) {
  return __builtin_amdgcn_rcpf(1.0f + __builtin_amdgcn_exp2f(-1.44269504f * z));
}
__device__ __forceinline__ float tanh_(float z) {
  return 1.0f - 2.0f * __builtin_amdgcn_rcpf(1.0f + __builtin_amdgcn_exp2f(2.88539008f * z));
}

__global__ __launch_bounds__(512, 2)
void lstm_mfma_kernel(const float* __restrict__ x,
                      const float* __restrict__ Wi,
                      const float* __restrict__ Wh,
                      const float* __restrict__ bh,
                      const float* __restrict__ Wo,
                      const float* __restrict__ bo,
                      float* __restrict__ out) {
  const int t    = threadIdx.x;      // 0..511
  const int lane = t & 63;
  const int w    = t >> 6;           // wave 0..7
  const int b    = blockIdx.x;
  const int lmod = lane & 15;        // row (A) / col (B) index within tile
  const int lgrp = lane >> 4;        // k-group 0..3

  // LDS: HxBuf[0..191] = [h(128)|x(64)] fp16; [192..199] = 16B zero region.
  __shared__ __align__(16) _Float16 HxBuf[208];
  __shared__ float Z[LSTM_G];        // gate pre-activations (no bias)

  // ---- stage B fragments (one-time): wave w covers cols [64w, 64w+64) ----
  // frag[nt][kk]: elem j = W[k][n], k = 32*kk + 8*lgrp + j, n = 64w+16nt+lmod
  f16x8 Bf[4][6];
  #pragma unroll
  for (int nt = 0; nt < 4; ++nt) {
    const int n = 64 * w + 16 * nt + lmod;
    #pragma unroll
    for (int kk = 0; kk < 6; ++kk) {
      union { f16x8 v; _Float16 e[8]; } uB;
      #pragma unroll
      for (int j = 0; j < 8; ++j) {
        const int k = 32 * kk + 8 * lgrp + j;
        const float val = (k < LSTM_H) ? Wh[(size_t)k * LSTM_G + n]
                                       : Wi[(size_t)(k - LSTM_H) * LSTM_G + n];
        uB.e[j] = (_Float16)val;
      }
      Bf[nt][kk] = uB.v;
    }
  }

  // bias registers for combine threads (t<128 handles unit u=t)
  float bb0 = 0.f, bb1 = 0.f, bb2 = 0.f, bb3 = 0.f;
  if (t < LSTM_H) {
    bb0 = bh[t];
    bb1 = bh[LSTM_H + t];
    bb2 = bh[2 * LSTM_H + t];
    bb3 = bh[3 * LSTM_H + t];
  }

  const float* xb = x + (size_t)b * (LSTM_S * LSTM_D);

  // x pipeline: at loop top of step s, xA = x_{s+1}, xB = x_{s+2}
  float xA = 0.f, xB = 0.f;
  if (w == 7) {
    xA = xb[1 * LSTM_D + lane];
    xB = xb[2 * LSTM_D + lane];
  }
  // init LDS: h = 0, x-part = x_0, zero region
  if (t < LSTM_H) HxBuf[t] = (_Float16)0.0f;
  if (w == 6) HxBuf[LSTM_H + lane] = (_Float16)xb[lane];
  if (t < 8) HxBuf[192 + t] = (_Float16)0.0f;

  // A-frag source: real lanes (lmod==0) walk Hx; junk lanes read the zero 16B
  const char* aBase = (lmod == 0)
      ? (const char*)HxBuf + 16 * lgrp
      : (const char*)HxBuf + 384;
  const int aStep = (lmod == 0) ? 64 : 0;   // bytes per k-step

  float c = 0.f, hval = 0.f;
  __syncthreads();

  for (int s = 0; s < LSTM_S; ++s) {
    // prefetch x_{s+3} (consumed at P4 of step s+1)
    float xnext = 0.f;
    if (w == 7) {
      int si = s + 3; if (si > LSTM_S - 1) si = LSTM_S - 1;
      xnext = xb[(size_t)si * LSTM_D + lane];
    }

    // ---- P1: A fragments from LDS ----
    f16x8 A0 = *(const f16x8*)(aBase);
    f16x8 A1 = *(const f16x8*)(aBase + 1 * aStep);
    f16x8 A2 = *(const f16x8*)(aBase + 2 * aStep);
    f16x8 A3 = *(const f16x8*)(aBase + 3 * aStep);
    f16x8 A4 = *(const f16x8*)(aBase + 4 * aStep);
    f16x8 A5 = *(const f16x8*)(aBase + 5 * aStep);

    // ---- MFMA: z for this wave's 64 cols ----
    f32x4 acc0 = {0.f, 0.f, 0.f, 0.f};
    f32x4 acc1 = {0.f, 0.f, 0.f, 0.f};
    f32x4 acc2 = {0.f, 0.f, 0.f, 0.f};
    f32x4 acc3 = {0.f, 0.f, 0.f, 0.f};
    #define MF(Ak, kk)                                                        \
      acc0 = __builtin_amdgcn_mfma_f32_16x16x32_f16(Ak, Bf[0][kk], acc0, 0, 0, 0); \
      acc1 = __builtin_amdgcn_mfma_f32_16x16x32_f16(Ak, Bf[1][kk], acc1, 0, 0, 0); \
      acc2 = __builtin_amdgcn_mfma_f32_16x16x32_f16(Ak, Bf[2][kk], acc2, 0, 0, 0); \
      acc3 = __builtin_amdgcn_mfma_f32_16x16x32_f16(Ak, Bf[3][kk], acc3, 0, 0, 0);
    MF(A0, 0) MF(A1, 1) MF(A2, 2) MF(A3, 3) MF(A4, 4) MF(A5, 5)
    #undef MF

    // ---- P2: extract row 0 (batch row): lanes 0-15, reg 0 ----
    if (lane < 16) {
      Z[64 * w + lane]      = acc0[0];
      Z[64 * w + 16 + lane] = acc1[0];
      Z[64 * w + 32 + lane] = acc2[0];
      Z[64 * w + 48 + lane] = acc3[0];
    }
    __syncthreads();                   // barrier 1: Z visible

    // ---- P4: gate combine (t<128) + x publish (wave 7) ----
    if (t < LSTM_H) {
      const float iv = sigm(Z[t] + bb0);
      const float fv = sigm(Z[LSTM_H + t] + bb1);
      const float gv = tanh_(Z[2 * LSTM_H + t] + bb2);
      const float ov = sigm(Z[3 * LSTM_H + t] + bb3);
      c = fv * c + iv * gv;
      hval = ov * tanh_(c);
      HxBuf[t] = (_Float16)hval;       // h for step s+1
    }
    if (w == 7) {
      HxBuf[LSTM_H + lane] = (_Float16)xA;  // x_{s+1}
      xA = xB;
      xB = xnext;
    }
    __syncthreads();                   // barrier 2: Hx ready for next step
  }

  // ---- output: out[b] = h_last @ Wo + bo ----
  if (t < LSTM_H) Z[t] = hval * Wo[t];
  __syncthreads();
  if (t < 64) {
    float v = Z[t] + Z[t + 64];
    #pragma unroll
    for (int off = 32; off; off >>= 1) v += __shfl_down(v, off);
    if (t == 0) out[b] = v + bo[0];
  }
}

extern "C" void kernel_launch(void* const* d_in, const int* in_sizes, int n_in,
                              void* d_out, int out_size, void* d_ws, size_t ws_size,
                              hipStream_t stream) {
  const float* x  = (const float*)d_in[0];
  const float* Wi = (const float*)d_in[1];
  const float* Wh = (const float*)d_in[2];
  const float* bh = (const float*)d_in[3];
  const float* Wo = (const float*)d_in[4];
  const float* bo = (const float*)d_in[5];
  float* out = (float*)d_out;

  lstm_mfma_kernel<<<LSTM_B, 512, 0, stream>>>(x, Wi, Wh, bh, Wo, bo, out);
}

// Round 10
// 2494.835 us; speedup vs baseline: 1.5843x; 1.0682x over previous
//
#include <hip/hip_runtime.h>
#include <hip/hip_fp16.h>

// LSTM: B=256, S=4096, D=64, H=128 (4H=512 gate cols [i|f|g|o]), K=192=[h;x].
// One batch element per block (256 blocks = 1/CU), 512 threads = 8 waves.
// z = [h;x] @ [Wh;Wi] via v_mfma_f32_16x16x32_f16, A = hx in row 0 only.
// KEY CHANGE vs R9: wave w's 4 n-tiles are gate g of units [16w,16w+16)
// (n = 128g + 16w + lmod), so lane<16 holds i,f,g,o of unit u=16w+lane
// in-register after the MFMA -> gate combine needs NO LDS regroup and the
// step needs ONE barrier (double-buffered Hx). A/B staging maps, C/D row-0
// extraction, and activation/c/h formulas identical to R9 (passed, 4.88e-4).

#define LSTM_B 256
#define LSTM_S 4096
#define LSTM_D 64
#define LSTM_H 128
#define LSTM_G 512

typedef _Float16 f16x8 __attribute__((ext_vector_type(8)));
typedef float f32x4 __attribute__((ext_vector_type(4)));

__device__ __forceinline__ float sigm(float z) {
  return __builtin_amdgcn_rcpf(1.0f + __builtin_amdgcn_exp2f(-1.44269504f * z));
}
__device__ __forceinline__ float tanh_(float z) {
  return 1.0f - 2.0f * __builtin_amdgcn_rcpf(1.0f + __builtin_amdgcn_exp2f(2.88539008f * z));
}

__global__ __launch_bounds__(512, 2)
void lstm_mfma_kernel(const float* __restrict__ x,
                      const float* __restrict__ Wi,
                      const float* __restrict__ Wh,
                      const float* __restrict__ bh,
                      const float* __restrict__ Wo,
                      const float* __restrict__ bo,
                      float* __restrict__ out) {
  const int t    = threadIdx.x;      // 0..511
  const int lane = t & 63;
  const int w    = t >> 6;           // wave 0..7
  const int b    = blockIdx.x;
  const int lmod = lane & 15;        // row (A) / col (B) index within tile
  const int lgrp = lane >> 4;        // k-group 0..3

  // double-buffered [h(128) | x(64) | zero(16)] fp16
  __shared__ __align__(16) _Float16 Hx[2][208];
  __shared__ float R[LSTM_H];        // final reduce

  // ---- stage B fragments: wave w, gate g -> cols n = 128g + 16w + lmod ----
  // elem j of frag[g][kk] = W[k][n], k = 32*kk + 8*lgrp + j  (same map as A)
  f16x8 Bf[4][6];
  #pragma unroll
  for (int g = 0; g < 4; ++g) {
    const int n = 128 * g + 16 * w + lmod;
    #pragma unroll
    for (int kk = 0; kk < 6; ++kk) {
      union { f16x8 v; _Float16 e[8]; } uB;
      #pragma unroll
      for (int j = 0; j < 8; ++j) {
        const int k = 32 * kk + 8 * lgrp + j;
        const float val = (k < LSTM_H) ? Wh[(size_t)k * LSTM_G + n]
                                       : Wi[(size_t)(k - LSTM_H) * LSTM_G + n];
        uB.e[j] = (_Float16)val;
      }
      Bf[g][kk] = uB.v;
    }
  }

  // biases for this thread's unit (lane<16: u = 16w + lane)
  const int u = 16 * w + lmod;
  float bb0 = 0.f, bb1 = 0.f, bb2 = 0.f, bb3 = 0.f;
  if (lane < 16) {
    bb0 = bh[u];
    bb1 = bh[LSTM_H + u];
    bb2 = bh[2 * LSTM_H + u];
    bb3 = bh[3 * LSTM_H + u];
  }

  const float* xb = x + (size_t)b * (LSTM_S * LSTM_D);

  // x pipeline: at loop top of step s, xA = x_{s+1}, xB = x_{s+2}
  float xA = 0.f, xB = 0.f;
  if (w == 7) {
    xA = xb[1 * LSTM_D + lane];
    xB = xb[2 * LSTM_D + lane];
  }
  // init buffer 0: h = 0, x = x_0; zero regions of both buffers
  if (t < LSTM_H) Hx[0][t] = (_Float16)0.0f;
  if (w == 6) Hx[0][LSTM_H + lane] = (_Float16)xb[lane];
  if (t < 16) { Hx[0][192 + t] = (_Float16)0.0f; Hx[1][192 + t] = (_Float16)0.0f; }

  float c = 0.f, hval = 0.f;
  __syncthreads();

  for (int s = 0; s < LSTM_S; ++s) {
    const int p = s & 1;               // read buffer
    // prefetch x_{s+3}
    float xnext = 0.f;
    if (w == 7) {
      int si = s + 3; if (si > LSTM_S - 1) si = LSTM_S - 1;
      xnext = xb[(size_t)si * LSTM_D + lane];
    }

    // A-frag source: lmod==0 lanes walk Hx[p]; junk lanes read the zero 16B
    const char* aBase = (lmod == 0)
        ? (const char*)&Hx[p][0] + 16 * lgrp
        : (const char*)&Hx[p][192];
    const int aStep = (lmod == 0) ? 64 : 0;

    f16x8 A0 = *(const f16x8*)(aBase);
    f16x8 A1 = *(const f16x8*)(aBase + 1 * aStep);
    f16x8 A2 = *(const f16x8*)(aBase + 2 * aStep);
    f16x8 A3 = *(const f16x8*)(aBase + 3 * aStep);
    f16x8 A4 = *(const f16x8*)(aBase + 4 * aStep);
    f16x8 A5 = *(const f16x8*)(aBase + 5 * aStep);

    // ---- MFMA: gates of this wave's 16 units ----
    f32x4 acc0 = {0.f, 0.f, 0.f, 0.f};
    f32x4 acc1 = {0.f, 0.f, 0.f, 0.f};
    f32x4 acc2 = {0.f, 0.f, 0.f, 0.f};
    f32x4 acc3 = {0.f, 0.f, 0.f, 0.f};
    #define MF(Ak, kk)                                                        \
      acc0 = __builtin_amdgcn_mfma_f32_16x16x32_f16(Ak, Bf[0][kk], acc0, 0, 0, 0); \
      acc1 = __builtin_amdgcn_mfma_f32_16x16x32_f16(Ak, Bf[1][kk], acc1, 0, 0, 0); \
      acc2 = __builtin_amdgcn_mfma_f32_16x16x32_f16(Ak, Bf[2][kk], acc2, 0, 0, 0); \
      acc3 = __builtin_amdgcn_mfma_f32_16x16x32_f16(Ak, Bf[3][kk], acc3, 0, 0, 0);
    MF(A0, 0) MF(A1, 1) MF(A2, 2) MF(A3, 3) MF(A4, 4) MF(A5, 5)
    #undef MF

    // ---- in-register gate combine: lane<16 holds row 0 (batch row) ----
    if (lane < 16) {
      const float iv = sigm(acc0[0] + bb0);
      const float fv = sigm(acc1[0] + bb1);
      const float gv = tanh_(acc2[0] + bb2);
      const float ov = sigm(acc3[0] + bb3);
      c = fv * c + iv * gv;
      hval = ov * tanh_(c);
      Hx[p ^ 1][u] = (_Float16)hval;   // h for step s+1
    }
    if (w == 7) {
      Hx[p ^ 1][LSTM_H + lane] = (_Float16)xA;  // x_{s+1}
      xA = xB;
      xB = xnext;
    }
    __syncthreads();                   // single barrier per step
  }

  // ---- output: out[b] = h_last @ Wo + bo ----
  if (lane < 16) R[u] = hval * Wo[u];
  __syncthreads();
  if (t < 64) {
    float v = R[t] + R[t + 64];
    #pragma unroll
    for (int off = 32; off; off >>= 1) v += __shfl_down(v, off);
    if (t == 0) out[b] = v + bo[0];
  }
}

extern "C" void kernel_launch(void* const* d_in, const int* in_sizes, int n_in,
                              void* d_out, int out_size, void* d_ws, size_t ws_size,
                              hipStream_t stream) {
  const float* x  = (const float*)d_in[0];
  const float* Wi = (const float*)d_in[1];
  const float* Wh = (const float*)d_in[2];
  const float* bh = (const float*)d_in[3];
  const float* Wo = (const float*)d_in[4];
  const float* bo = (const float*)d_in[5];
  float* out = (float*)d_out;

  lstm_mfma_kernel<<<LSTM_B, 512, 0, stream>>>(x, Wi, Wh, bh, Wo, bo, out);
}

// Round 11
// 2349.762 us; speedup vs baseline: 1.6821x; 1.0617x over previous
//
#include <hip/hip_runtime.h>
#include <hip/hip_fp16.h>

// LSTM: B=256, S=4096, D=64, H=128 (4H=512 gate cols [i|f|g|o]), K=192=[h;x].
// One batch element per block (256 blocks = 1/CU), 256 threads = 4 waves
// (1 wave/SIMD: no co-issue contention, 4-wave barrier).
// z = [h;x] @ [Wh;Wi] via v_mfma_f32_16x16x32_f16. A carries hx in row 0 AND
// row 4 (duplicate): row 0 -> lanes 0-15 reg0, row 4 -> lanes 16-31 reg0, so
// lanes 0-31 each own one unit's 4 gates via v_cndmask (NO cross-lane ops).
// Wave w owns gates g of units [32w,32w+32): n = 128g + 32w + 16hh + lmod,
// nt = 2g+hh. Split-K accumulators (kk 0-2 -> accA, 3-5 -> accB): 16
// independent MFMA chains/wave, dep distance 8 insts.
// A/B staged with the SAME (lgrp,j)->k map (cancellation, proven R9/R10).
// Activation/c/h formulas identical to passing rounds (absmax 4.88e-4).

#define LSTM_B 256
#define LSTM_S 4096
#define LSTM_D 64
#define LSTM_H 128
#define LSTM_G 512

typedef _Float16 f16x8 __attribute__((ext_vector_type(8)));
typedef float f32x4 __attribute__((ext_vector_type(4)));

__device__ __forceinline__ float sigm(float z) {
  return __builtin_amdgcn_rcpf(1.0f + __builtin_amdgcn_exp2f(-1.44269504f * z));
}
__device__ __forceinline__ float tanh_(float z) {
  return 1.0f - 2.0f * __builtin_amdgcn_rcpf(1.0f + __builtin_amdgcn_exp2f(2.88539008f * z));
}

__global__ __launch_bounds__(256, 1)
void lstm_mfma_kernel(const float* __restrict__ x,
                      const float* __restrict__ Wi,
                      const float* __restrict__ Wh,
                      const float* __restrict__ bh,
                      const float* __restrict__ Wo,
                      const float* __restrict__ bo,
                      float* __restrict__ out) {
  const int t    = threadIdx.x;      // 0..255
  const int lane = t & 63;
  const int w    = t >> 6;           // wave 0..3
  const int b    = blockIdx.x;
  const int lmod = lane & 15;        // row (A) / col (B) index within tile
  const int lgrp = lane >> 4;        // k-group 0..3

  // double-buffered [h(128) | x(64) | zero(16)] fp16
  __shared__ __align__(16) _Float16 Hx[2][208];
  __shared__ float R[LSTM_H];        // final reduce

  // ---- stage B fragments: nt = 2g+hh -> cols n = 128g + 32w + 16hh + lmod
  // elem j of Bf[nt][kk] = W[k][n], k = 32*kk + 8*lgrp + j (same map as A)
  f16x8 Bf[8][6];
  #pragma unroll
  for (int g = 0; g < 4; ++g) {
    #pragma unroll
    for (int hh = 0; hh < 2; ++hh) {
      const int nt = 2 * g + hh;
      const int n = 128 * g + 32 * w + 16 * hh + lmod;
      #pragma unroll
      for (int kk = 0; kk < 6; ++kk) {
        union { f16x8 v; _Float16 e[8]; } uB;
        #pragma unroll
        for (int j = 0; j < 8; ++j) {
          const int k = 32 * kk + 8 * lgrp + j;
          const float val = (k < LSTM_H) ? Wh[(size_t)k * LSTM_G + n]
                                         : Wi[(size_t)(k - LSTM_H) * LSTM_G + n];
          uB.e[j] = (_Float16)val;
        }
        Bf[nt][kk] = uB.v;
      }
    }
  }

  // biases for this thread's unit (lanes<32: u = 32w + (lane&31))
  const int ul = 32 * w + (lane & 31);
  const float bb0 = bh[ul];
  const float bb1 = bh[LSTM_H + ul];
  const float bb2 = bh[2 * LSTM_H + ul];
  const float bb3 = bh[3 * LSTM_H + ul];

  const float* xb = x + (size_t)b * (LSTM_S * LSTM_D);

  // x pipeline: at loop top of step s, xA = x_{s+1}, xB = x_{s+2}
  float xA = 0.f, xB = 0.f;
  if (w == 3) {
    xA = xb[1 * LSTM_D + lane];
    xB = xb[2 * LSTM_D + lane];
  }
  // init buffer 0: h = 0, x = x_0; zero regions of both buffers
  if (t < LSTM_H) Hx[0][t] = (_Float16)0.0f;
  if (w == 1) Hx[0][LSTM_H + lane] = (_Float16)xb[lane];
  if (t < 16) { Hx[0][192 + t] = (_Float16)0.0f; Hx[1][192 + t] = (_Float16)0.0f; }

  // A rows 0 and 4 carry hx (duplicate); all other rows read the zero 16B
  const bool areal = (lmod == 0) || (lmod == 4);
  const int aOff  = areal ? 16 * lgrp : 384;   // byte offset within Hx[p]
  const int aStep = areal ? 64 : 0;            // bytes per k-step

  float c = 0.f, hval = 0.f;
  __syncthreads();

  for (int s = 0; s < LSTM_S; ++s) {
    const int p = s & 1;               // read buffer
    // prefetch x_{s+3}
    float xnext = 0.f;
    if (w == 3) {
      int si = s + 3; if (si > LSTM_S - 1) si = LSTM_S - 1;
      xnext = xb[(size_t)si * LSTM_D + lane];
    }

    const char* aBase = (const char*)&Hx[p][0] + aOff;
    f16x8 A0 = *(const f16x8*)(aBase);
    f16x8 A1 = *(const f16x8*)(aBase + 1 * aStep);
    f16x8 A2 = *(const f16x8*)(aBase + 2 * aStep);
    f16x8 A3 = *(const f16x8*)(aBase + 3 * aStep);
    f16x8 A4 = *(const f16x8*)(aBase + 4 * aStep);
    f16x8 A5 = *(const f16x8*)(aBase + 5 * aStep);

    // ---- MFMA: 8 n-tiles x 6 k-steps, split-K (A: kk 0-2, B: kk 3-5) ----
    f32x4 accA[8], accB[8];
    #pragma unroll
    for (int n = 0; n < 8; ++n) {
      accA[n] = (f32x4){0.f, 0.f, 0.f, 0.f};
      accB[n] = (f32x4){0.f, 0.f, 0.f, 0.f};
    }
    #define MFK(Ak, kk, ACC)                                                   \
      _Pragma("unroll")                                                        \
      for (int n = 0; n < 8; ++n)                                              \
        ACC[n] = __builtin_amdgcn_mfma_f32_16x16x32_f16(Ak, Bf[n][kk], ACC[n], 0, 0, 0);
    MFK(A0, 0, accA) MFK(A1, 1, accA) MFK(A2, 2, accA)
    MFK(A3, 3, accB) MFK(A4, 4, accB) MFK(A5, 5, accB)
    #undef MFK

    // ---- in-register gate combine on lanes 0-31 ----
    // lane<16: row0 (hh=0 tile, nt=2g); lane 16-31: row4 (hh=1 tile, nt=2g+1)
    {
      const bool hsel = (lane & 16) != 0;
      const float zi0 = accA[0][0] + accB[0][0], zi1 = accA[1][0] + accB[1][0];
      const float zf0 = accA[2][0] + accB[2][0], zf1 = accA[3][0] + accB[3][0];
      const float zg0 = accA[4][0] + accB[4][0], zg1 = accA[5][0] + accB[5][0];
      const float zo0 = accA[6][0] + accB[6][0], zo1 = accA[7][0] + accB[7][0];
      const float iv = sigm((hsel ? zi1 : zi0) + bb0);
      const float fv = sigm((hsel ? zf1 : zf0) + bb1);
      const float gv = tanh_((hsel ? zg1 : zg0) + bb2);
      const float ov = sigm((hsel ? zo1 : zo0) + bb3);
      c = fv * c + iv * gv;
      hval = ov * tanh_(c);
      if (lane < 32) Hx[p ^ 1][ul] = (_Float16)hval;   // h for step s+1
    }
    if (w == 3) {
      Hx[p ^ 1][LSTM_H + lane] = (_Float16)xA;  // x_{s+1}
      xA = xB;
      xB = xnext;
    }
    __syncthreads();                   // single barrier per step
  }

  // ---- output: out[b] = h_last @ Wo + bo ----
  if (lane < 32) R[ul] = hval * Wo[ul];
  __syncthreads();
  if (t < 64) {
    float v = R[t] + R[t + 64];
    #pragma unroll
    for (int off = 32; off; off >>= 1) v += __shfl_down(v, off);
    if (t == 0) out[b] = v + bo[0];
  }
}

extern "C" void kernel_launch(void* const* d_in, const int* in_sizes, int n_in,
                              void* d_out, int out_size, void* d_ws, size_t ws_size,
                              hipStream_t stream) {
  const float* x  = (const float*)d_in[0];
  const float* Wi = (const float*)d_in[1];
  const float* Wh = (const float*)d_in[2];
  const float* bh = (const float*)d_in[3];
  const float* Wo = (const float*)d_in[4];
  const float* bo = (const float*)d_in[5];
  float* out = (float*)d_out;

  lstm_mfma_kernel<<<LSTM_B, 256, 0, stream>>>(x, Wi, Wh, bh, Wo, bo, out);
}